// Round 6
// baseline (164.969 us; speedup 1.0000x reference)
//
#include <hip/hip_runtime.h>
#include <math.h>

// B=4, C=64, H=W=128, O=64, K=3, pad=1, stride=1
// Round-6: LDS-free fused kernel fed by a one-time NHWC-bf16 copy of x.
//   k_nhwc : NCHW fp32 -> NHWC bf16 (xb, 8.4 MB, L3-resident)
//   k_pack : weights -> bf16 fragment-feed layouts (L2-resident)
//   k_fused: per 8x8 tile: offset-conv MFMA (A direct from xb) -> P_s (7 KB LDS)
//            -> in-register bilinear sampling (corners direct from xb) + main MFMA GEMM
// ws: xb 8.39 MB + wtB + pgwB  (~8.5 MB; Round-4 proven safe)

typedef __attribute__((ext_vector_type(8))) short short8;   // 8 bf16 (A/B frag)
typedef __attribute__((ext_vector_type(4))) float f32x4;    // C/D frag

#define BWP 584   // pgwB row stride (576+8)

__device__ __forceinline__ float b2f(unsigned short h) {
    union { unsigned u; float f; } v; v.u = ((unsigned)h) << 16; return v.f;
}
__device__ __forceinline__ unsigned short f2b(float f) {   // RNE
    union { float f; unsigned u; } v; v.f = f;
    unsigned r = v.u + 0x7FFFu + ((v.u >> 16) & 1u);
    return (unsigned short)(r >> 16);
}

// ---------------- K0: NCHW fp32 -> NHWC bf16 ----------------
// 512 blocks = (b, h). Coalesced row reads -> LDS -> coalesced 16B NHWC writes.
__global__ __launch_bounds__(256) void k_nhwc(const float* __restrict__ x,
                                              unsigned short* __restrict__ xb) {
    __shared__ float tile[64][130];
    int bh = blockIdx.x;            // b*128 + h
    int b = bh >> 7, h = bh & 127;
    int t = threadIdx.x;
    for (int idx = t; idx < 8192; idx += 256) {
        int c = idx >> 7, w = idx & 127;
        tile[c][w] = x[((b * 64 + c) * 128 + h) * 128 + w];
    }
    __syncthreads();
    for (int idx = t; idx < 1024; idx += 256) {
        int w = idx >> 3, c0 = (idx & 7) * 8;
        short8 v;
#pragma unroll
        for (int e = 0; e < 8; ++e) v[e] = (short)f2b(tile[c0 + e][w]);
        *(short8*)&xb[((size_t)bh * 128 + w) * 64 + c0] = v;
    }
}

// ---------------- K1: pack weights to bf16 ----------------
// wtB [kk][o][c] (9*64*64);  pgwB[pp][q*64+c] stride 584 (32 rows, zero-padded)
__global__ __launch_bounds__(256) void k_pack_w(const float* __restrict__ weight,
                                                const float* __restrict__ pg_w,
                                                unsigned short* __restrict__ wtB,
                                                unsigned short* __restrict__ pgwB) {
    int idx = blockIdx.x * 256 + threadIdx.x;
    if (idx < 36864) {
        int c = idx & 63, o = (idx >> 6) & 63, kk = idx >> 12;
        wtB[idx] = f2b(weight[(o * 64 + c) * 9 + kk]);
    }
    int i2 = idx - 36864;
    if (i2 >= 0 && i2 < 32 * BWP) {
        int pp = i2 / BWP, k = i2 - pp * BWP;
        float v = 0.f;
        if (pp < 27 && k < 576) {
            int q = k >> 6, c = k & 63;
            v = pg_w[(pp * 64 + c) * 9 + q];
        }
        pgwB[i2] = f2b(v);
    }
}

// ---------------- K2: fused offset-conv + deformable conv (LDS-free A/B) ----------------
// 1024 blocks (b x 16 x 16), tile = 8x8 px. 256 threads = 4 waves.
__global__ __launch_bounds__(256, 4) void k_fused(const unsigned short* __restrict__ xb,
                                                  const unsigned short* __restrict__ pgwB,
                                                  const float* __restrict__ pg_b,
                                                  const unsigned short* __restrict__ wtB,
                                                  const float* __restrict__ bias,
                                                  float* __restrict__ out) {
    __shared__ float P_s[27 * 65];   // 7.0 KB [param][px]

    int bid = blockIdx.x;
    int b  = bid >> 8;
    int h0 = ((bid >> 4) & 15) * 8;
    int w0 = (bid & 15) * 8;
    int t = threadIdx.x;
    int l = t & 63, w = t >> 6;
    int quad = l >> 4, ln = l & 15;
    const unsigned short* xbb = xb + (size_t)b * 16384 * 64;

    int px = w * 16 + ln;                 // this lane's m-row pixel (A-side)
    int py = px >> 3, pxx = px & 7;
    int hh = h0 + py, ww = w0 + pxx;

    // ---- phase 1: offset conv MFMA (M=64, N=32, K=576), A direct from xb ----
    {
        f32x4 o0 = {0.f, 0.f, 0.f, 0.f}, o1 = {0.f, 0.f, 0.f, 0.f};
#pragma unroll
        for (int kb = 0; kb < 18; ++kb) {
            int q = kb >> 1;
            int kh = q / 3, kw = q - 3 * (q / 3);
            int k0 = kb * 32 + quad * 8;
            short8 b0 = *(const short8*)&pgwB[ln * BWP + k0];           // L2-hot
            short8 b1 = *(const short8*)&pgwB[(16 + ln) * BWP + k0];
            int gy = hh + kh - 1, gx = ww + kw - 1;
            bool valid = ((unsigned)gy < 128u) && ((unsigned)gx < 128u);
            int gyc = min(max(gy, 0), 127), gxc = min(max(gx, 0), 127);
            int c0 = (kb & 1) * 32 + quad * 8;
            short8 af = *(const short8*)&xbb[(gyc * 128 + gxc) * 64 + c0];
            if (!valid) af = (short8)0;   // conv zero-padding
            o0 = __builtin_amdgcn_mfma_f32_16x16x32_bf16(af, b0, o0, 0, 0, 0);
            o1 = __builtin_amdgcn_mfma_f32_16x16x32_bf16(af, b1, o1, 0, 0, 0);
        }
        // D: col = param = tile*16+ln; row(local) = quad*4+i; px = w*16+row
#pragma unroll
        for (int tile = 0; tile < 2; ++tile) {
            int p = tile * 16 + ln;
            f32x4 a = tile ? o1 : o0;
            if (p < 27) {
                float bo = pg_b[p];
#pragma unroll
                for (int i = 0; i < 4; ++i) {
                    int wpx = w * 16 + quad * 4 + i;
                    float v = a[i] + bo;
                    if (p >= 18) v = 1.f / (1.f + expf(-v));
                    P_s[p * 65 + wpx] = v;
                }
            }
        }
    }
    __syncthreads();

    // ---- phase 2: in-register bilinear sampling + main GEMM (M=64,N=64,K=576) ----
    f32x4 acc[4];
#pragma unroll
    for (int nt = 0; nt < 4; ++nt) acc[nt] = (f32x4){0.f, 0.f, 0.f, 0.f};

    for (int kk = 0; kk < 9; ++kk) {
        // B fragments per-lane from global (L2-hot), issue early
        const unsigned short* wk = wtB + kk * 4096;
        short8 bfr[2][4];
#pragma unroll
        for (int kb = 0; kb < 2; ++kb)
#pragma unroll
            for (int nt = 0; nt < 4; ++nt)
                bfr[kb][nt] = *(const short8*)&wk[(nt * 16 + ln) * 64 + kb * 32 + quad * 8];

        // bilinear params from LDS
        int ki = kk / 3, kj = kk - 3 * (kk / 3);
        float dyv = P_s[(2 * kk) * 65 + px];
        float dxv = P_s[(2 * kk + 1) * 65 + px];
        float m   = P_s[(18 + kk) * 65 + px];
        float ys = (float)(hh - 1 + ki) + dyv;
        float xs = (float)(ww - 1 + kj) + dxv;
        float y0f = floorf(ys), x0f = floorf(xs);
        int y0 = (int)y0f, x0 = (int)x0f;
        float ly = ys - y0f, lx = xs - x0f;
        float v0y = ((unsigned)y0 < 128u) ? 1.f : 0.f;
        float v1y = ((unsigned)(y0 + 1) < 128u) ? 1.f : 0.f;
        float v0x = ((unsigned)x0 < 128u) ? 1.f : 0.f;
        float v1x = ((unsigned)(x0 + 1) < 128u) ? 1.f : 0.f;
        float w00 = (1.f - ly) * (1.f - lx) * v0y * v0x * m;
        float w01 = (1.f - ly) * lx * v0y * v1x * m;
        float w10 = ly * (1.f - lx) * v1y * v0x * m;
        float w11 = ly * lx * v1y * v1x * m;

        int y0c = min(max(y0, 0), 127), y1c = min(max(y0 + 1, 0), 127);
        int x0c = min(max(x0, 0), 127), x1c = min(max(x0 + 1, 0), 127);
        int base00 = (y0c * 128 + x0c) * 64;
        int dxo = (x1c - x0c) * 64;
        int dyo = (y1c - y0c) * 8192;

        // issue all 8 corner loads (16B each), then convert
        short8 r[2][4];
#pragma unroll
        for (int kb = 0; kb < 2; ++kb) {
            int c0 = kb * 32 + quad * 8;
            r[kb][0] = *(const short8*)&xbb[base00 + c0];
            r[kb][1] = *(const short8*)&xbb[base00 + dxo + c0];
            r[kb][2] = *(const short8*)&xbb[base00 + dyo + c0];
            r[kb][3] = *(const short8*)&xbb[base00 + dyo + dxo + c0];
        }
        short8 af[2];
#pragma unroll
        for (int kb = 0; kb < 2; ++kb)
#pragma unroll
            for (int e = 0; e < 8; ++e) {
                float v = w00 * b2f((unsigned short)r[kb][0][e])
                        + w01 * b2f((unsigned short)r[kb][1][e])
                        + w10 * b2f((unsigned short)r[kb][2][e])
                        + w11 * b2f((unsigned short)r[kb][3][e]);
                af[kb][e] = (short)f2b(v);
            }

#pragma unroll
        for (int kb = 0; kb < 2; ++kb)
#pragma unroll
            for (int nt = 0; nt < 4; ++nt)
                acc[nt] = __builtin_amdgcn_mfma_f32_16x16x32_bf16(af[kb], bfr[kb][nt], acc[nt], 0, 0, 0);
    }

    // ---- epilogue: lane's 4 rows per nt are 4 consecutive ww -> float4 store ----
    int px0 = w * 16 + quad * 4;
    int ehh = h0 + (px0 >> 3), eww = w0 + (px0 & 7);
#pragma unroll
    for (int nt = 0; nt < 4; ++nt) {
        int o = nt * 16 + ln;
        float bo = bias[o];
        float4 v;
        v.x = acc[nt][0] + bo; v.y = acc[nt][1] + bo;
        v.z = acc[nt][2] + bo; v.w = acc[nt][3] + bo;
        *(float4*)&out[((size_t)b * 64 + o) * 16384 + ehh * 128 + eww] = v;
    }
}

extern "C" void kernel_launch(void* const* d_in, const int* in_sizes, int n_in,
                              void* d_out, int out_size, void* d_ws, size_t ws_size,
                              hipStream_t stream) {
    const float* x      = (const float*)d_in[0];
    const float* weight = (const float*)d_in[1];
    const float* bias   = (const float*)d_in[2];
    const float* pg_w   = (const float*)d_in[3];
    const float* pg_b   = (const float*)d_in[4];
    float* out = (float*)d_out;

    unsigned short* xbB  = (unsigned short*)d_ws;        // 4*16384*64 = 4,194,304 bf16 (8.39 MB)
    unsigned short* wtB  = xbB + (size_t)4 * 16384 * 64; // 36,864 bf16
    unsigned short* pgwB = wtB + 36864;                  // 32*584 bf16   (~8.5 MB total)

    k_nhwc<<<512, 256, 0, stream>>>(x, xbB);
    k_pack_w<<<218, 256, 0, stream>>>(weight, pg_w, wtB, pgwB);
    k_fused<<<1024, 256, 0, stream>>>(xbB, pgwB, pg_b, wtB, bias, out);
}

// Round 7
// 124.321 us; speedup vs baseline: 1.3270x; 1.3270x over previous
//
#include <hip/hip_runtime.h>
#include <math.h>

// B=4, C=64, H=W=128, O=64, K=3, pad=1, stride=1
// Round-7: NHWC-bf16 xb (R6) + LDS patch staged FROM xb with coalesced b128 copies (fixes
// R5's strided staging) + in-register bilinear sampling + MFMA GEMMs (R5 compute structure).
// ws: xb 8.39 MB + wtB + pgwB  (~8.5 MB)

typedef __attribute__((ext_vector_type(8))) short short8;   // 8 bf16 (A/B frag)
typedef __attribute__((ext_vector_type(4))) float f32x4;    // C/D frag

#define BWP 584   // pgwB row stride (576+8)

__device__ __forceinline__ float b2f(unsigned short h) {
    union { unsigned u; float f; } v; v.u = ((unsigned)h) << 16; return v.f;
}
__device__ __forceinline__ unsigned short f2b(float f) {   // RNE
    union { float f; unsigned u; } v; v.f = f;
    unsigned r = v.u + 0x7FFFu + ((v.u >> 16) & 1u);
    return (unsigned short)(r >> 16);
}

// ---------------- K0: NCHW fp32 -> NHWC bf16 ----------------
// 2048 blocks = (b, h, w-quarter). Coalesced reads -> LDS -> coalesced 16B NHWC writes.
__global__ __launch_bounds__(256) void k_nhwc(const float* __restrict__ x,
                                              unsigned short* __restrict__ xb) {
    __shared__ float tile[64][33];
    int bid = blockIdx.x;
    int b = bid >> 9, h = (bid >> 2) & 127, w0 = (bid & 3) * 32;
    int t = threadIdx.x;
    for (int idx = t; idx < 2048; idx += 256) {
        int c = idx >> 5, w = idx & 31;
        tile[c][w] = x[((b * 64 + c) * 128 + h) * 128 + w0 + w];
    }
    __syncthreads();
    {
        int wl = t >> 3, c0 = (t & 7) * 8;
        short8 v;
#pragma unroll
        for (int e = 0; e < 8; ++e) v[e] = (short)f2b(tile[c0 + e][wl]);
        *(short8*)&xb[(((size_t)b * 128 + h) * 128 + w0 + wl) * 64 + c0] = v;
    }
}

// ---------------- K1: pack weights to bf16 ----------------
// wtB [kk][o][c] (9*64*64);  pgwB[pp][q*64+c] stride 584 (32 rows, zero-padded)
__global__ __launch_bounds__(256) void k_pack_w(const float* __restrict__ weight,
                                                const float* __restrict__ pg_w,
                                                unsigned short* __restrict__ wtB,
                                                unsigned short* __restrict__ pgwB) {
    int idx = blockIdx.x * 256 + threadIdx.x;
    if (idx < 36864) {
        int c = idx & 63, o = (idx >> 6) & 63, kk = idx >> 12;
        wtB[idx] = f2b(weight[(o * 64 + c) * 9 + kk]);
    }
    int i2 = idx - 36864;
    if (i2 >= 0 && i2 < 32 * BWP) {
        int pp = i2 / BWP, k = i2 - pp * BWP;
        float v = 0.f;
        if (pp < 27 && k < 576) {
            int q = k >> 6, c = k & 63;
            v = pg_w[(pp * 64 + c) * 9 + q];
        }
        pgwB[i2] = f2b(v);
    }
}

// ---------------- K2: fused offset-conv + deformable conv ----------------
// 1024 blocks (b x 16 x 16), tile = 8x8 px. 256 threads = 4 waves.
// Patch rows h0-2..h0+10 (13), cols w0-2..w0+11 (14); staged from xb (coalesced).
__global__ __launch_bounds__(256, 4) void k_fused(const unsigned short* __restrict__ xb,
                                                  const unsigned short* __restrict__ pgwB,
                                                  const float* __restrict__ pg_b,
                                                  const unsigned short* __restrict__ wtB,
                                                  const float* __restrict__ bias,
                                                  float* __restrict__ out) {
    __shared__ unsigned short patch[182 * 64];   // 23.3 KB [pos=yy*14+xx][c ^ (pos&7)*8]
    __shared__ float P_s[27 * 65];               // 7.0 KB  [param][px]

    int bid = blockIdx.x;
    int b  = bid >> 8;
    int h0 = ((bid >> 4) & 15) * 8;
    int w0 = (bid & 15) * 8;
    int t = threadIdx.x;
    int base_y = h0 - 2, base_x = w0 - 2;
    const unsigned short* xbb = xb + (size_t)b * 16384 * 64;

    // ---- phase 0: stage patch from xb; 1456 b128 chunks, coalesced ----
    for (int i = t; i < 1456; i += 256) {
        int yy = i / 112;
        int r  = i - yy * 112;
        int xx = r >> 3;
        int c0 = (r & 7) * 8;
        int gy = base_y + yy, gx = base_x + xx;
        int pos = yy * 14 + xx;
        short8 v = (short8)0;
        if (((unsigned)gy < 128u) && ((unsigned)gx < 128u))
            v = *(const short8*)&xbb[(gy * 128 + gx) * 64 + c0];
        *(short8*)&patch[pos * 64 + (c0 ^ ((pos & 7) * 8))] = v;
    }
    __syncthreads();

    int l = t & 63, w = t >> 6;
    int quad = l >> 4, ln = l & 15;
    int px = w * 16 + ln;                 // this lane's m-row pixel (A-side)
    int py = px >> 3, pxx = px & 7;
    int hh = h0 + py, ww = w0 + pxx;

    // ---- phase 1: offset conv MFMA (M=64, N=32, K=576), A from patch ----
    {
        f32x4 o0 = {0.f, 0.f, 0.f, 0.f}, o1 = {0.f, 0.f, 0.f, 0.f};
#pragma unroll
        for (int kb = 0; kb < 18; ++kb) {
            int q = kb >> 1;
            int kh = q / 3, kw = q - 3 * (q / 3);
            int k0 = kb * 32 + quad * 8;
            short8 b0 = *(const short8*)&pgwB[ln * BWP + k0];           // L2-hot
            short8 b1 = *(const short8*)&pgwB[(16 + ln) * BWP + k0];
            int aoff = (py + kh + 1) * 14 + (pxx + kw + 1);
            int c0 = (kb & 1) * 32 + quad * 8;
            short8 af = *(const short8*)&patch[aoff * 64 + (c0 ^ ((aoff & 7) * 8))];
            o0 = __builtin_amdgcn_mfma_f32_16x16x32_bf16(af, b0, o0, 0, 0, 0);
            o1 = __builtin_amdgcn_mfma_f32_16x16x32_bf16(af, b1, o1, 0, 0, 0);
        }
#pragma unroll
        for (int tile = 0; tile < 2; ++tile) {
            int p = tile * 16 + ln;
            f32x4 a = tile ? o1 : o0;
            if (p < 27) {
                float bo = pg_b[p];
#pragma unroll
                for (int i = 0; i < 4; ++i) {
                    int wpx = w * 16 + quad * 4 + i;
                    float v = a[i] + bo;
                    if (p >= 18) v = 1.f / (1.f + expf(-v));
                    P_s[p * 65 + wpx] = v;
                }
            }
        }
    }
    __syncthreads();

    // ---- phase 2: in-register bilinear sampling + main GEMM (M=64,N=64,K=576) ----
    f32x4 acc[4];
#pragma unroll
    for (int nt = 0; nt < 4; ++nt) acc[nt] = (f32x4){0.f, 0.f, 0.f, 0.f};

    for (int kk = 0; kk < 9; ++kk) {
        // B fragments per-lane from global (L2-hot), issue early
        const unsigned short* wk = wtB + kk * 4096;
        short8 bfr[2][4];
#pragma unroll
        for (int kb = 0; kb < 2; ++kb)
#pragma unroll
            for (int nt = 0; nt < 4; ++nt)
                bfr[kb][nt] = *(const short8*)&wk[(nt * 16 + ln) * 64 + kb * 32 + quad * 8];

        // bilinear params from LDS
        int ki = kk / 3, kj = kk - 3 * (kk / 3);
        float dyv = P_s[(2 * kk) * 65 + px];
        float dxv = P_s[(2 * kk + 1) * 65 + px];
        float m   = P_s[(18 + kk) * 65 + px];
        float ys = (float)(hh - 1 + ki) + dyv;
        float xs = (float)(ww - 1 + kj) + dxv;
        float y0f = floorf(ys), x0f = floorf(xs);
        int y0 = (int)y0f, x0 = (int)x0f;
        float ly = ys - y0f, lx = xs - x0f;
        float v0y = ((unsigned)y0 < 128u) ? 1.f : 0.f;
        float v1y = ((unsigned)(y0 + 1) < 128u) ? 1.f : 0.f;
        float v0x = ((unsigned)x0 < 128u) ? 1.f : 0.f;
        float v1x = ((unsigned)(x0 + 1) < 128u) ? 1.f : 0.f;
        float w00 = (1.f - ly) * (1.f - lx) * v0y * v0x * m;
        float w01 = (1.f - ly) * lx * v0y * v1x * m;
        float w10 = ly * (1.f - lx) * v1y * v0x * m;
        float w11 = ly * lx * v1y * v1x * m;
        int ly0 = y0 - base_y, lx0 = x0 - base_x;
        bool inp = ((unsigned)ly0 < 12u) && ((unsigned)lx0 < 12u);

        short8 af[2];
        if (inp) {
            int pos = ly0 * 14 + lx0;
#pragma unroll
            for (int kb = 0; kb < 2; ++kb) {
                int c0 = kb * 32 + quad * 8;
                short8 r00 = *(const short8*)&patch[pos * 64 + (c0 ^ ((pos & 7) * 8))];
                short8 r01 = *(const short8*)&patch[(pos + 1) * 64 + (c0 ^ (((pos + 1) & 7) * 8))];
                short8 r10 = *(const short8*)&patch[(pos + 14) * 64 + (c0 ^ (((pos + 14) & 7) * 8))];
                short8 r11 = *(const short8*)&patch[(pos + 15) * 64 + (c0 ^ (((pos + 15) & 7) * 8))];
#pragma unroll
                for (int e = 0; e < 8; ++e) {
                    float v = w00 * b2f((unsigned short)r00[e]) + w01 * b2f((unsigned short)r01[e])
                            + w10 * b2f((unsigned short)r10[e]) + w11 * b2f((unsigned short)r11[e]);
                    af[kb][e] = (short)f2b(v);
                }
            }
        } else {   // rare (|offset| >= 1): direct xb reads, clamped corners (same bf16 values)
            int y0c = min(max(y0, 0), 127), y1c = min(max(y0 + 1, 0), 127);
            int x0c = min(max(x0, 0), 127), x1c = min(max(x0 + 1, 0), 127);
            int base00 = (y0c * 128 + x0c) * 64;
            int dxo = (x1c - x0c) * 64, dyo = (y1c - y0c) * 8192;
#pragma unroll
            for (int kb = 0; kb < 2; ++kb) {
                int c0 = kb * 32 + quad * 8;
                short8 r00 = *(const short8*)&xbb[base00 + c0];
                short8 r01 = *(const short8*)&xbb[base00 + dxo + c0];
                short8 r10 = *(const short8*)&xbb[base00 + dyo + c0];
                short8 r11 = *(const short8*)&xbb[base00 + dyo + dxo + c0];
#pragma unroll
                for (int e = 0; e < 8; ++e) {
                    float v = w00 * b2f((unsigned short)r00[e]) + w01 * b2f((unsigned short)r01[e])
                            + w10 * b2f((unsigned short)r10[e]) + w11 * b2f((unsigned short)r11[e]);
                    af[kb][e] = (short)f2b(v);
                }
            }
        }

#pragma unroll
        for (int kb = 0; kb < 2; ++kb)
#pragma unroll
            for (int nt = 0; nt < 4; ++nt)
                acc[nt] = __builtin_amdgcn_mfma_f32_16x16x32_bf16(af[kb], bfr[kb][nt], acc[nt], 0, 0, 0);
    }

    // ---- epilogue: lane's 4 rows per nt are 4 consecutive ww -> float4 store ----
    int px0 = w * 16 + quad * 4;
    int ehh = h0 + (px0 >> 3), eww = w0 + (px0 & 7);
#pragma unroll
    for (int nt = 0; nt < 4; ++nt) {
        int o = nt * 16 + ln;
        float bo = bias[o];
        float4 v;
        v.x = acc[nt][0] + bo; v.y = acc[nt][1] + bo;
        v.z = acc[nt][2] + bo; v.w = acc[nt][3] + bo;
        *(float4*)&out[((size_t)b * 64 + o) * 16384 + ehh * 128 + eww] = v;
    }
}

extern "C" void kernel_launch(void* const* d_in, const int* in_sizes, int n_in,
                              void* d_out, int out_size, void* d_ws, size_t ws_size,
                              hipStream_t stream) {
    const float* x      = (const float*)d_in[0];
    const float* weight = (const float*)d_in[1];
    const float* bias   = (const float*)d_in[2];
    const float* pg_w   = (const float*)d_in[3];
    const float* pg_b   = (const float*)d_in[4];
    float* out = (float*)d_out;

    unsigned short* xbB  = (unsigned short*)d_ws;        // 4*16384*64 bf16 (8.39 MB)
    unsigned short* wtB  = xbB + (size_t)4 * 16384 * 64; // 36,864 bf16
    unsigned short* pgwB = wtB + 36864;                  // 32*584 bf16   (~8.5 MB total)

    k_nhwc<<<2048, 256, 0, stream>>>(x, xbB);
    k_pack_w<<<218, 256, 0, stream>>>(weight, pg_w, wtB, pgwB);
    k_fused<<<1024, 256, 0, stream>>>(xbB, pgwB, pg_b, wtB, bias, out);
}